// Round 2
// baseline (742.523 us; speedup 1.0000x reference)
//
#include <hip/hip_runtime.h>
#include <hip/hip_cooperative_groups.h>
#include <math.h>

namespace cg = cooperative_groups;

#define LP 800
#define DP 200
#define HP 100
#define MP 256   // P*K
#define MM1 255

typedef float fx4 __attribute__((ext_vector_type(4)));

// d_out offsets (floats), reference return order
#define OFF_SCS  0u
#define OFF_R    40960000u
#define OFF_ENC  40985600u
#define OFF_V    41190400u
#define OFF_TIL  41255680u

// workspace offsets (floats)
#define WS_C     0u        // 25600
#define WS_O     25600u    // 25600
#define WS_S     51200u    // 65280  (s_rows, row-major [i][jp])

// S_Cs stream: 256 m * 40000 fx4 units. sid = (m, chunk): chunk = 2048
// units (8 per thread), 20 chunks/m (chunk 19 = 1088 units, guarded).
#define SCS_TOTAL 5120

// Fused cooperative kernel geometry
#define GRID  1024
#define PRE_A (GRID - MP)               // 768 sids streamed during phase 1
#define PRE_B (GRID - MM1)              // 769 sids streamed during phase 2
#define REM   (SCS_TOTAL - PRE_A - PRE_B)  // 3583 sids streamed after phase 3

// Legacy 3-kernel fallback split
#define SCS_B1 1707
#define SCS_B2 1707
#define SCS_B3 1706
#define NB1 0
#define NB2 1707
#define NB3 3414

__device__ __forceinline__ float tanh_fast(float x) {
    // tanh(x) = 1 - 2/(exp(2x)+1); exact at both saturation ends.
    float e = __expf(2.0f * x);
    return 1.0f - 2.0f / (e + 1.0f);
}

// one scs chunk: 8 fx4 per thread, 2048 consecutive units within one m.
// Loads batched before stores for max outstanding-request depth per wave.
__device__ __forceinline__ void scs_slice(const fx4* __restrict__ Sp4,
                                          const int* __restrict__ spans,
                                          fx4* __restrict__ out4,
                                          unsigned sid) {
    unsigned m     = sid / 20u;
    unsigned chunk = sid - m * 20u;
    unsigned p = m >> 1, k = m & 1;
    int start = spans[p * 4 + k * 2];
    int end   = spans[p * 4 + k * 2 + 1];
    const fx4* __restrict__ src = Sp4 + (size_t)p * 40000u;
    fx4* __restrict__ dst       = out4 + (size_t)m * 40000u;
    unsigned base = chunk * 2048u + threadIdx.x;

    if (chunk < 19u) {          // full chunk: no bounds checks (block-uniform)
        fx4 v[8];
        #pragma unroll
        for (int it = 0; it < 8; ++it) {
            unsigned off = base + (unsigned)it * 256u;
            int t = (int)(off / 50u);       // 50 fx4 per D-row
            fx4 x = (fx4)(0.f);
            if (t >= start && t <= end) x = src[off];
            v[it] = x;
        }
        #pragma unroll
        for (int it = 0; it < 8; ++it) {
            unsigned off = base + (unsigned)it * 256u;
            __builtin_nontemporal_store(v[it], &dst[off]);
        }
    } else {                    // tail chunk: 1088 units
        #pragma unroll
        for (int it = 0; it < 8; ++it) {
            unsigned off = base + (unsigned)it * 256u;
            if (off < 40000u) {
                int t = (int)(off / 50u);
                fx4 x = (fx4)(0.f);
                if (t >= start && t <= end) x = src[off];
                __builtin_nontemporal_store(x, &dst[off]);
            }
        }
    }
}

// ============================ fused cooperative kernel ======================
__global__ __launch_bounds__(256, 4) void fused_kernel(
        const float* __restrict__ Sp,
        const int* __restrict__ spans,
        const int* __restrict__ passages,
        const float* __restrict__ Wb,
        const float* __restrict__ We,
        const float* __restrict__ Wc,
        const float* __restrict__ Wo,
        const float* __restrict__ Wv,
        float* __restrict__ enc,
        float* __restrict__ r_out,
        float* __restrict__ V_out,
        float* __restrict__ til_out,
        float* __restrict__ c_ws,
        float* __restrict__ o_ws,
        float* __restrict__ s_ws,
        fx4* __restrict__ out4) {
    __shared__ float4 sb4[50], se4[50], rs4[25];          // phase 1
    __shared__ float4 olo4[25], ohi4[25], wv4[25];        // phase 2
    __shared__ float part[4];                             // phase 2
    __shared__ float srow[MM1 + 1];                       // phase 3

    cg::grid_group grid = cg::this_grid();
    const int bid = blockIdx.x;
    const int tid = threadIdx.x;

    // -------- Phase 1: enc + r + c/o on blocks 0..255; others stream ------
    if (bid < MP) {
        int m = bid;
        int p = m >> 1, k = m & 1;
        int start = spans[p * 4 + k * 2];
        int end   = spans[p * 4 + k * 2 + 1];

        int len = end - start;
        for (int t = tid; t < LP; t += 256) {
            int g = start + t; if (g > LP - 1) g = LP - 1;
            enc[m * LP + t] = (t <= len) ? (float)passages[p * LP + g] : 0.f;
        }

        const float4* sbp = (const float4*)(Sp + (size_t)(p * LP + start) * DP);
        const float4* sep = (const float4*)(Sp + (size_t)(p * LP + end) * DP);
        if (tid < 50)       sb4[tid]      = sbp[tid];
        else if (tid < 100) se4[tid - 50] = sep[tid - 50];
        __syncthreads();

        int h = tid;
        if (h < HP) {
            const float4* wb = (const float4*)(Wb + h * DP);
            const float4* we = (const float4*)(We + h * DP);
            float acc = 0.f;
            #pragma unroll
            for (int d = 0; d < 50; ++d) {
                float4 a = sb4[d], b = wb[d];
                acc += a.x * b.x + a.y * b.y + a.z * b.z + a.w * b.w;
                float4 a2 = se4[d], b2 = we[d];
                acc += a2.x * b2.x + a2.y * b2.y + a2.z * b2.z + a2.w * b2.w;
            }
            float r = tanh_fast(acc);
            ((float*)rs4)[h] = r;
            r_out[m * HP + h] = r;
        }
        __syncthreads();
        if (h < HP) {
            const float4* wc = (const float4*)(Wc + h * HP);
            const float4* wo = (const float4*)(Wo + h * HP);
            float accc = 0.f, acco = 0.f;
            #pragma unroll
            for (int q = 0; q < 25; ++q) {
                float4 r = rs4[q], cc = wc[q], oo = wo[q];
                accc += r.x * cc.x + r.y * cc.y + r.z * cc.z + r.w * cc.w;
                acco += r.x * oo.x + r.y * oo.y + r.z * oo.z + r.w * oo.w;
            }
            c_ws[m * HP + h] = accc;
            o_ws[m * HP + h] = acco;
        }
    } else {
        // sids [4352, 5120)
        scs_slice((const fx4*)Sp, spans, out4,
                  (unsigned)(SCS_TOTAL - 1) - (unsigned)(bid - MP));
    }
    __threadfence();
    grid.sync();

    // -------- Phase 2: V + alpha + s_rows on blocks 0..254; others stream --
    if (bid < MM1) {
        int jp = bid;
        int i = tid;
        if (i < 25) {
            olo4[i] = ((const float4*)(o_ws + jp * HP))[i];
            ohi4[i] = ((const float4*)(o_ws + (jp + 1) * HP))[i];
            wv4[i]  = ((const float4*)Wv)[i];
        }
        __syncthreads();

        const float4* c4p = (const float4*)(c_ws + i * HP);
        bool hi = (jp >= i);
        float acc = 0.f;
        #pragma unroll
        for (int q = 0; q < 25; ++q) {
            float4 c4 = c4p[q];
            float4 o4 = hi ? ohi4[q] : olo4[q];
            float4 w4 = wv4[q];
            acc += tanh_fast(c4.x + o4.x) * w4.x;
            acc += tanh_fast(c4.y + o4.y) * w4.y;
            acc += tanh_fast(c4.z + o4.z) * w4.z;
            acc += tanh_fast(c4.w + o4.w) * w4.w;
        }
        V_out[i * MM1 + jp] = acc;
        float e = __expf(acc);

        float v = e;
        v += __shfl_down(v, 32); v += __shfl_down(v, 16); v += __shfl_down(v, 8);
        v += __shfl_down(v, 4);  v += __shfl_down(v, 2);  v += __shfl_down(v, 1);
        if ((i & 63) == 0) part[i >> 6] = v;
        __syncthreads();
        float colE = part[0] + part[1] + part[2] + part[3];

        float a = e / (colE - e);

        __syncthreads();
        float v2 = a;
        v2 += __shfl_down(v2, 32); v2 += __shfl_down(v2, 16); v2 += __shfl_down(v2, 8);
        v2 += __shfl_down(v2, 4);  v2 += __shfl_down(v2, 2);  v2 += __shfl_down(v2, 1);
        if ((i & 63) == 0) part[i >> 6] = v2;
        __syncthreads();
        float colA = part[0] + part[1] + part[2] + part[3];

        s_ws[i * MM1 + jp] = colA - a;
    } else {
        // sids [3583, 4352)
        scs_slice((const fx4*)Sp, spans, out4,
                  (unsigned)(SCS_TOTAL - PRE_A - 1) - (unsigned)(bid - MM1));
    }
    __threadfence();
    grid.sync();

    // -------- Phase 3: tilda on blocks 0..255 (no barrier after) -----------
    if (bid < MP) {
        int i = bid;
        for (int jp = tid; jp < MM1; jp += 256)
            srow[jp] = s_ws[i * MM1 + jp];
        __syncthreads();
        int h = tid;
        if (h < HP) {
            float acc = 0.f;
            #pragma unroll 4
            for (int jp = 0; jp < i; ++jp)
                acc += srow[jp] * r_out[jp * HP + h];
            #pragma unroll 4
            for (int jp = i; jp < MM1; ++jp)
                acc += srow[jp] * r_out[(jp + 1) * HP + h];
            til_out[i * HP + h] = acc;
        }
    }

    // -------- Main stream: sids [0, 3583) ----------------------------------
    for (unsigned sid = (unsigned)bid; sid < (unsigned)REM; sid += (unsigned)GRID)
        scs_slice((const fx4*)Sp, spans, out4, sid);
}

// ============================ legacy 3-kernel fallback ======================
__global__ __launch_bounds__(256) void node1_kernel(const float* __restrict__ Sp,
                                                    const int* __restrict__ spans,
                                                    const int* __restrict__ passages,
                                                    const float* __restrict__ Wb,
                                                    const float* __restrict__ We,
                                                    const float* __restrict__ Wc,
                                                    const float* __restrict__ Wo,
                                                    float* __restrict__ enc,
                                                    float* __restrict__ r_out,
                                                    float* __restrict__ c_ws,
                                                    float* __restrict__ o_ws,
                                                    fx4* __restrict__ out4) {
    if (blockIdx.x >= MP) {
        scs_slice((const fx4*)Sp, spans, out4, NB1 + blockIdx.x - MP);
        return;
    }
    __shared__ float4 sb4[50], se4[50], rs4[25];
    int m = blockIdx.x;
    int p = m >> 1, k = m & 1;
    int start = spans[p * 4 + k * 2];
    int end   = spans[p * 4 + k * 2 + 1];
    int tid = threadIdx.x;

    int len = end - start;
    for (int t = tid; t < LP; t += 256) {
        int g = start + t; if (g > LP - 1) g = LP - 1;
        enc[m * LP + t] = (t <= len) ? (float)passages[p * LP + g] : 0.f;
    }

    const float4* sbp = (const float4*)(Sp + (size_t)(p * LP + start) * DP);
    const float4* sep = (const float4*)(Sp + (size_t)(p * LP + end) * DP);
    if (tid < 50)       sb4[tid]      = sbp[tid];
    else if (tid < 100) se4[tid - 50] = sep[tid - 50];
    __syncthreads();

    int h = tid;
    if (h < HP) {
        const float4* wb = (const float4*)(Wb + h * DP);
        const float4* we = (const float4*)(We + h * DP);
        float acc = 0.f;
        #pragma unroll
        for (int d = 0; d < 50; ++d) {
            float4 a = sb4[d], b = wb[d];
            acc += a.x * b.x + a.y * b.y + a.z * b.z + a.w * b.w;
            float4 a2 = se4[d], b2 = we[d];
            acc += a2.x * b2.x + a2.y * b2.y + a2.z * b2.z + a2.w * b2.w;
        }
        float r = tanh_fast(acc);
        ((float*)rs4)[h] = r;
        r_out[m * HP + h] = r;
    }
    __syncthreads();
    if (h < HP) {
        const float4* wc = (const float4*)(Wc + h * HP);
        const float4* wo = (const float4*)(Wo + h * HP);
        float accc = 0.f, acco = 0.f;
        #pragma unroll
        for (int q = 0; q < 25; ++q) {
            float4 r = rs4[q], cc = wc[q], oo = wo[q];
            accc += r.x * cc.x + r.y * cc.y + r.z * cc.z + r.w * cc.w;
            acco += r.x * oo.x + r.y * oo.y + r.z * oo.z + r.w * oo.w;
        }
        c_ws[m * HP + h] = accc;
        o_ws[m * HP + h] = acco;
    }
}

__global__ __launch_bounds__(256) void node2_kernel(const float* __restrict__ Sp,
                                                    const int* __restrict__ spans,
                                                    const float* __restrict__ c_ws,
                                                    const float* __restrict__ o_ws,
                                                    const float* __restrict__ Wv,
                                                    float* __restrict__ V_out,
                                                    float* __restrict__ s_ws,
                                                    fx4* __restrict__ out4) {
    if (blockIdx.x >= MM1) {
        scs_slice((const fx4*)Sp, spans, out4, NB2 + blockIdx.x - MM1);
        return;
    }
    __shared__ float4 olo4[25], ohi4[25], wv4[25];
    __shared__ float part[4];
    int jp = blockIdx.x;
    int i = threadIdx.x;
    if (i < 25) {
        olo4[i] = ((const float4*)(o_ws + jp * HP))[i];
        ohi4[i] = ((const float4*)(o_ws + (jp + 1) * HP))[i];
        wv4[i]  = ((const float4*)Wv)[i];
    }
    __syncthreads();

    const float4* c4p = (const float4*)(c_ws + i * HP);
    bool hi = (jp >= i);
    float acc = 0.f;
    #pragma unroll
    for (int q = 0; q < 25; ++q) {
        float4 c4 = c4p[q];
        float4 o4 = hi ? ohi4[q] : olo4[q];
        float4 w4 = wv4[q];
        acc += tanh_fast(c4.x + o4.x) * w4.x;
        acc += tanh_fast(c4.y + o4.y) * w4.y;
        acc += tanh_fast(c4.z + o4.z) * w4.z;
        acc += tanh_fast(c4.w + o4.w) * w4.w;
    }
    V_out[i * MM1 + jp] = acc;
    float e = __expf(acc);

    float v = e;
    v += __shfl_down(v, 32); v += __shfl_down(v, 16); v += __shfl_down(v, 8);
    v += __shfl_down(v, 4);  v += __shfl_down(v, 2);  v += __shfl_down(v, 1);
    if ((i & 63) == 0) part[i >> 6] = v;
    __syncthreads();
    float colE = part[0] + part[1] + part[2] + part[3];

    float a = e / (colE - e);

    __syncthreads();
    float v2 = a;
    v2 += __shfl_down(v2, 32); v2 += __shfl_down(v2, 16); v2 += __shfl_down(v2, 8);
    v2 += __shfl_down(v2, 4);  v2 += __shfl_down(v2, 2);  v2 += __shfl_down(v2, 1);
    if ((i & 63) == 0) part[i >> 6] = v2;
    __syncthreads();
    float colA = part[0] + part[1] + part[2] + part[3];

    s_ws[i * MM1 + jp] = colA - a;
}

__global__ __launch_bounds__(256) void node3_kernel(const float* __restrict__ Sp,
                                                    const int* __restrict__ spans,
                                                    const float* __restrict__ s_ws,
                                                    const float* __restrict__ r_out,
                                                    float* __restrict__ til_out,
                                                    fx4* __restrict__ out4) {
    if (blockIdx.x >= MP) {
        scs_slice((const fx4*)Sp, spans, out4, NB3 + blockIdx.x - MP);
        return;
    }
    __shared__ float s[MM1 + 1];
    int i = blockIdx.x;
    for (int jp = threadIdx.x; jp < MM1; jp += 256)
        s[jp] = s_ws[i * MM1 + jp];
    __syncthreads();
    int h = threadIdx.x;
    if (h < HP) {
        float acc = 0.f;
        #pragma unroll 4
        for (int jp = 0; jp < i; ++jp)
            acc += s[jp] * r_out[jp * HP + h];
        #pragma unroll 4
        for (int jp = i; jp < MM1; ++jp)
            acc += s[jp] * r_out[(jp + 1) * HP + h];
        til_out[i * HP + h] = acc;
    }
}

extern "C" void kernel_launch(void* const* d_in, const int* in_sizes, int n_in,
                              void* d_out, int out_size, void* d_ws, size_t ws_size,
                              hipStream_t stream) {
    const float* S_p      = (const float*)d_in[0];
    const int*   spans    = (const int*)d_in[1];
    const int*   passages = (const int*)d_in[2];
    const float* Wb       = (const float*)d_in[3];
    const float* We       = (const float*)d_in[4];
    const float* Wc       = (const float*)d_in[5];
    const float* Wo       = (const float*)d_in[6];
    const float* Wv       = (const float*)d_in[7];

    float* out = (float*)d_out;
    float* ws  = (float*)d_ws;

    float* out_scs = out + OFF_SCS;
    float* out_r   = out + OFF_R;
    float* out_enc = out + OFF_ENC;
    float* out_v   = out + OFF_V;
    float* out_til = out + OFF_TIL;

    float* ws_c = ws + WS_C;
    float* ws_o = ws + WS_O;
    float* ws_s = ws + WS_S;

    fx4* out4 = (fx4*)out_scs;

    void* args[] = {
        (void*)&S_p, (void*)&spans, (void*)&passages,
        (void*)&Wb, (void*)&We, (void*)&Wc, (void*)&Wo, (void*)&Wv,
        (void*)&out_enc, (void*)&out_r, (void*)&out_v, (void*)&out_til,
        (void*)&ws_c, (void*)&ws_o, (void*)&ws_s, (void*)&out4
    };
    hipError_t err = hipLaunchCooperativeKernel((const void*)fused_kernel,
                                                dim3(GRID), dim3(256),
                                                args, 0, stream);
    if (err != hipSuccess) {
        // Fallback: proven 3-kernel path.
        node1_kernel<<<MP + SCS_B1, 256, 0, stream>>>(S_p, spans, passages,
                                                      Wb, We, Wc, Wo,
                                                      out_enc, out_r, ws_c, ws_o, out4);
        node2_kernel<<<MM1 + SCS_B2, 256, 0, stream>>>(S_p, spans, ws_c, ws_o, Wv,
                                                       out_v, ws_s, out4);
        node3_kernel<<<MP + SCS_B3, 256, 0, stream>>>(S_p, spans, ws_s, out_r,
                                                      out_til, out4);
    }
}

// Round 3
// 270.476 us; speedup vs baseline: 2.7452x; 2.7452x over previous
//
#include <hip/hip_runtime.h>
#include <math.h>

#define LP 800
#define DP 200
#define HP 100
#define MP 256   // P*K
#define MM1 255

typedef float fx4 __attribute__((ext_vector_type(4)));

// d_out offsets (floats), reference return order
#define OFF_SCS  0u
#define OFF_R    40960000u
#define OFF_ENC  40985600u
#define OFF_V    41190400u
#define OFF_TIL  41255680u

// workspace offsets (floats)
#define WS_C     0u        // 25600
#define WS_O     25600u    // 25600
#define WS_S     51200u    // 65280  (s_rows, row-major [i][jp])

// S_Cs stream: 256 m * 40000 fx4 units. sid = (m, chunk): chunk = 2048
// units (8 per thread), 20 chunks/m (chunk 19 = 1088 units, guarded).
// 5120 sids split across the 3 chain nodes.
#define SCS_TOTAL 5120
#define SCS_B1 1707
#define SCS_B2 1707
#define SCS_B3 1706
#define NB1 0
#define NB2 1707
#define NB3 3414

__device__ __forceinline__ float tanh_fast(float x) {
    // tanh(x) = 1 - 2/(exp(2x)+1); exact at both saturation ends.
    float e = __expf(2.0f * x);
    return 1.0f - 2.0f / (e + 1.0f);
}

// one scs chunk: 8 fx4 per thread, 2048 consecutive units within one m.
// Regular (cached) stores: L2 write-combining path, same as the 6.4 TB/s
// fill kernel. (A/B vs nontemporal stores of rounds 0-1.)
__device__ __forceinline__ void scs_slice(const fx4* __restrict__ Sp4,
                                          const int* __restrict__ spans,
                                          fx4* __restrict__ out4,
                                          unsigned sid) {
    unsigned m     = sid / 20u;
    unsigned chunk = sid - m * 20u;
    unsigned p = m >> 1, k = m & 1;
    int start = spans[p * 4 + k * 2];
    int end   = spans[p * 4 + k * 2 + 1];
    const fx4* __restrict__ src = Sp4 + (size_t)p * 40000u;
    fx4* __restrict__ dst       = out4 + (size_t)m * 40000u;
    unsigned base = chunk * 2048u + threadIdx.x;

    if (chunk < 19u) {          // full chunk: no bounds checks (block-uniform)
        fx4 v[8];
        #pragma unroll
        for (int it = 0; it < 8; ++it) {
            unsigned off = base + (unsigned)it * 256u;
            int t = (int)(off / 50u);       // 50 fx4 per D-row
            fx4 x = (fx4)(0.f);
            if (t >= start && t <= end) x = src[off];
            v[it] = x;
        }
        #pragma unroll
        for (int it = 0; it < 8; ++it) {
            unsigned off = base + (unsigned)it * 256u;
            dst[off] = v[it];
        }
    } else {                    // tail chunk: 1088 units
        #pragma unroll
        for (int it = 0; it < 8; ++it) {
            unsigned off = base + (unsigned)it * 256u;
            if (off < 40000u) {
                int t = (int)(off / 50u);
                fx4 x = (fx4)(0.f);
                if (t >= start && t <= end) x = src[off];
                dst[off] = x;
            }
        }
    }
}

// ---------------- Node 1: enc + r + c + o (blocks 0..255) + scs slice ------
__global__ __launch_bounds__(256) void node1_kernel(const float* __restrict__ Sp,
                                                    const int* __restrict__ spans,
                                                    const int* __restrict__ passages,
                                                    const float* __restrict__ Wb,
                                                    const float* __restrict__ We,
                                                    const float* __restrict__ Wc,
                                                    const float* __restrict__ Wo,
                                                    float* __restrict__ enc,
                                                    float* __restrict__ r_out,
                                                    float* __restrict__ c_ws,
                                                    float* __restrict__ o_ws,
                                                    fx4* __restrict__ out4) {
    if (blockIdx.x >= MP) {
        scs_slice((const fx4*)Sp, spans, out4, NB1 + blockIdx.x - MP);
        return;
    }
    __shared__ float4 sb4[50], se4[50], rs4[25];
    int m = blockIdx.x;
    int p = m >> 1, k = m & 1;
    int start = spans[p * 4 + k * 2];
    int end   = spans[p * 4 + k * 2 + 1];
    int tid = threadIdx.x;

    int len = end - start;
    for (int t = tid; t < LP; t += 256) {
        int g = start + t; if (g > LP - 1) g = LP - 1;
        enc[m * LP + t] = (t <= len) ? (float)passages[p * LP + g] : 0.f;
    }

    const float4* sbp = (const float4*)(Sp + (size_t)(p * LP + start) * DP);
    const float4* sep = (const float4*)(Sp + (size_t)(p * LP + end) * DP);
    if (tid < 50)       sb4[tid]      = sbp[tid];
    else if (tid < 100) se4[tid - 50] = sep[tid - 50];
    __syncthreads();

    int h = tid;
    if (h < HP) {
        const float4* wb = (const float4*)(Wb + h * DP);
        const float4* we = (const float4*)(We + h * DP);
        float acc = 0.f;
        #pragma unroll
        for (int d = 0; d < 50; ++d) {
            float4 a = sb4[d], b = wb[d];
            acc += a.x * b.x + a.y * b.y + a.z * b.z + a.w * b.w;
            float4 a2 = se4[d], b2 = we[d];
            acc += a2.x * b2.x + a2.y * b2.y + a2.z * b2.z + a2.w * b2.w;
        }
        float r = tanh_fast(acc);
        ((float*)rs4)[h] = r;
        r_out[m * HP + h] = r;
    }
    __syncthreads();
    if (h < HP) {
        const float4* wc = (const float4*)(Wc + h * HP);
        const float4* wo = (const float4*)(Wo + h * HP);
        float accc = 0.f, acco = 0.f;
        #pragma unroll
        for (int q = 0; q < 25; ++q) {
            float4 r = rs4[q], cc = wc[q], oo = wo[q];
            accc += r.x * cc.x + r.y * cc.y + r.z * cc.z + r.w * cc.w;
            acco += r.x * oo.x + r.y * oo.y + r.z * oo.z + r.w * oo.w;
        }
        c_ws[m * HP + h] = accc;
        o_ws[m * HP + h] = acco;
    }
}

// ---------------- Node 2: V + E + alpha + s_rows (blocks 0..254) + scs -----
__global__ __launch_bounds__(256) void node2_kernel(const float* __restrict__ Sp,
                                                    const int* __restrict__ spans,
                                                    const float* __restrict__ c_ws,
                                                    const float* __restrict__ o_ws,
                                                    const float* __restrict__ Wv,
                                                    float* __restrict__ V_out,
                                                    float* __restrict__ s_ws,
                                                    fx4* __restrict__ out4) {
    if (blockIdx.x >= MM1) {
        scs_slice((const fx4*)Sp, spans, out4, NB2 + blockIdx.x - MM1);
        return;
    }
    __shared__ float4 olo4[25], ohi4[25], wv4[25];
    __shared__ float part[4];
    int jp = blockIdx.x;
    int i = threadIdx.x;
    if (i < 25) {
        olo4[i] = ((const float4*)(o_ws + jp * HP))[i];
        ohi4[i] = ((const float4*)(o_ws + (jp + 1) * HP))[i];
        wv4[i]  = ((const float4*)Wv)[i];
    }
    __syncthreads();

    const float4* c4p = (const float4*)(c_ws + i * HP);
    bool hi = (jp >= i);
    float acc = 0.f;
    #pragma unroll
    for (int q = 0; q < 25; ++q) {
        float4 c4 = c4p[q];
        float4 o4 = hi ? ohi4[q] : olo4[q];
        float4 w4 = wv4[q];
        acc += tanh_fast(c4.x + o4.x) * w4.x;
        acc += tanh_fast(c4.y + o4.y) * w4.y;
        acc += tanh_fast(c4.z + o4.z) * w4.z;
        acc += tanh_fast(c4.w + o4.w) * w4.w;
    }
    V_out[i * MM1 + jp] = acc;
    float e = __expf(acc);

    float v = e;
    v += __shfl_down(v, 32); v += __shfl_down(v, 16); v += __shfl_down(v, 8);
    v += __shfl_down(v, 4);  v += __shfl_down(v, 2);  v += __shfl_down(v, 1);
    if ((i & 63) == 0) part[i >> 6] = v;
    __syncthreads();
    float colE = part[0] + part[1] + part[2] + part[3];

    float a = e / (colE - e);

    __syncthreads();
    float v2 = a;
    v2 += __shfl_down(v2, 32); v2 += __shfl_down(v2, 16); v2 += __shfl_down(v2, 8);
    v2 += __shfl_down(v2, 4);  v2 += __shfl_down(v2, 2);  v2 += __shfl_down(v2, 1);
    if ((i & 63) == 0) part[i >> 6] = v2;
    __syncthreads();
    float colA = part[0] + part[1] + part[2] + part[3];

    s_ws[i * MM1 + jp] = colA - a;
}

// ---------------- Node 3: tilda (blocks 0..255) + scs slice ----------------
__global__ __launch_bounds__(256) void node3_kernel(const float* __restrict__ Sp,
                                                    const int* __restrict__ spans,
                                                    const float* __restrict__ s_ws,
                                                    const float* __restrict__ r_out,
                                                    float* __restrict__ til_out,
                                                    fx4* __restrict__ out4) {
    if (blockIdx.x >= MP) {
        scs_slice((const fx4*)Sp, spans, out4, NB3 + blockIdx.x - MP);
        return;
    }
    __shared__ float s[MM1 + 1];
    int i = blockIdx.x;
    for (int jp = threadIdx.x; jp < MM1; jp += 256)
        s[jp] = s_ws[i * MM1 + jp];
    __syncthreads();
    int h = threadIdx.x;
    if (h < HP) {
        float acc = 0.f;
        #pragma unroll 4
        for (int jp = 0; jp < i; ++jp)
            acc += s[jp] * r_out[jp * HP + h];
        #pragma unroll 4
        for (int jp = i; jp < MM1; ++jp)
            acc += s[jp] * r_out[(jp + 1) * HP + h];
        til_out[i * HP + h] = acc;
    }
}

extern "C" void kernel_launch(void* const* d_in, const int* in_sizes, int n_in,
                              void* d_out, int out_size, void* d_ws, size_t ws_size,
                              hipStream_t stream) {
    const float* S_p      = (const float*)d_in[0];
    const int*   spans    = (const int*)d_in[1];
    const int*   passages = (const int*)d_in[2];
    const float* Wb       = (const float*)d_in[3];
    const float* We       = (const float*)d_in[4];
    const float* Wc       = (const float*)d_in[5];
    const float* Wo       = (const float*)d_in[6];
    const float* Wv       = (const float*)d_in[7];

    float* out = (float*)d_out;
    float* ws  = (float*)d_ws;

    float* out_scs = out + OFF_SCS;
    float* out_r   = out + OFF_R;
    float* out_enc = out + OFF_ENC;
    float* out_v   = out + OFF_V;
    float* out_til = out + OFF_TIL;

    float* ws_c = ws + WS_C;
    float* ws_o = ws + WS_O;
    float* ws_s = ws + WS_S;

    fx4* out4 = (fx4*)out_scs;

    node1_kernel<<<MP + SCS_B1, 256, 0, stream>>>(S_p, spans, passages,
                                                  Wb, We, Wc, Wo,
                                                  out_enc, out_r, ws_c, ws_o, out4);
    node2_kernel<<<MM1 + SCS_B2, 256, 0, stream>>>(S_p, spans, ws_c, ws_o, Wv,
                                                   out_v, ws_s, out4);
    node3_kernel<<<MP + SCS_B3, 256, 0, stream>>>(S_p, spans, ws_s, out_r,
                                                  out_til, out4);
}